// Round 5
// baseline (294.937 us; speedup 1.0000x reference)
//
#include <hip/hip_runtime.h>
#include <hip/hip_bf16.h>
#include <stdint.h>

// Self-attention, B=2 T=2048 C=1024 H=16 DH=64, causal + relative bias.
// Round 5: AITER-style pipelined K-loops in gemm_body and attn64 —
// double-buffered LDS, prefetch issued before the wait, s_waitcnt vmcnt(4)
// (never 0 in steady state), raw s_barrier. Mode-2 epilogue packs 8B stores.
// Invariants: dual-dtype external loads (flag), ws <= 256B + 22MB.
//
// ws layout (offsets from ws+256, bytes):
//   phase A: WqT @0..2M, WkT @2..4M, WvT @4..6M, K @6..14M, V^T @14..22M
//   phase B (weights/K dead): Y @0..8M, WoT @8..10M

#define T_SEQ 2048
#define NH    16
#define DHD   64
#define CDIM  1024

typedef unsigned short u16;
typedef unsigned int   u32;
typedef __attribute__((ext_vector_type(8))) __bf16 bf16x8;   // MFMA A/B operand
typedef __attribute__((ext_vector_type(4))) float f32x4;     // MFMA C/D operand

#define WAITV4L0 asm volatile("s_waitcnt vmcnt(4) lgkmcnt(0)" ::: "memory")
#define WAITV2L0 asm volatile("s_waitcnt vmcnt(2) lgkmcnt(0)" ::: "memory")
#define WAITV0L0 asm volatile("s_waitcnt vmcnt(0) lgkmcnt(0)" ::: "memory")
#define WAITV4   asm volatile("s_waitcnt vmcnt(4)" ::: "memory")
#define WAITV2   asm volatile("s_waitcnt vmcnt(2)" ::: "memory")
#define WAITV0   asm volatile("s_waitcnt vmcnt(0)" ::: "memory")
#define WAITL0   asm volatile("s_waitcnt lgkmcnt(0)" ::: "memory")
#define BARRIER  asm volatile("s_barrier" ::: "memory")

__device__ __forceinline__ float bf2f(u16 b){
  union { u32 u; float f; } v; v.u = ((u32)b) << 16; return v.f;
}
__device__ __forceinline__ u16 f2bf(float f){
  union { float f; u32 u; } v; v.f = f;
  u32 r = v.u + 0x7fffu + ((v.u >> 16) & 1u);   // RTNE
  return (u16)(r >> 16);
}

// async global->LDS, 16B per lane; LDS dest = wave-uniform base + lane*16B.
__device__ __forceinline__ void async16(const void* g, void* l){
  __builtin_amdgcn_global_load_lds(
      (const __attribute__((address_space(1))) unsigned int*)g,
      (__attribute__((address_space(3))) unsigned int*)l, 16, 0, 0);
}

// load 8 consecutive elements as packed bf16 (uint4), from bf16 or f32 source
__device__ __forceinline__ uint4 load8(const void* p, long elem, int isbf){
  if (isbf) return *(const uint4*)((const u16*)p + elem);
  const float* fp = (const float*)p + elem;
  float4 a = *(const float4*)fp, b = *(const float4*)(fp + 4);
  uint4 r;
  r.x = (u32)f2bf(a.x) | ((u32)f2bf(a.y) << 16);
  r.y = (u32)f2bf(a.z) | ((u32)f2bf(a.w) << 16);
  r.z = (u32)f2bf(b.x) | ((u32)f2bf(b.y) << 16);
  r.w = (u32)f2bf(b.z) | ((u32)f2bf(b.w) << 16);
  return r;
}
__device__ __forceinline__ float loadf(const void* p, long idx, int isbf){
  return isbf ? bf2f(((const u16*)p)[idx]) : ((const float*)p)[idx];
}

// ---------------- dtype classifier ------------------------------------------
__global__ __launch_bounds__(256) void classify(const u32* __restrict__ x,
                                                int* __restrict__ flag){
  __shared__ int cnt[256];
  int c = 0;
#pragma unroll
  for (int i = 0; i < 16; i++){
    u32 w = x[threadIdx.x * 16 + i];
    int e = (w >> 7) & 0xFF;
    c += (e >= 110 && e <= 140);
  }
  cnt[threadIdx.x] = c;
  __syncthreads();
  for (int s = 128; s > 0; s >>= 1){
    if ((int)threadIdx.x < s) cnt[threadIdx.x] += cnt[threadIdx.x + s];
    __syncthreads();
  }
  if (threadIdx.x == 0) *flag = (cnt[0] > 2048) ? 1 : 0;   // 1 = bf16
}

// ---------------- weight transpose: out[n][k] = in[k][n], 1024x1024 ----------
__global__ __launch_bounds__(256) void transposeW(
    const void* __restrict__ w0, const void* __restrict__ w1,
    const void* __restrict__ w2,
    u16* __restrict__ o0, u16* __restrict__ o1, u16* __restrict__ o2,
    const int* __restrict__ flag)
{
  __shared__ u16 tile[64][72];
  const int isbf = *flag;
  const int z = blockIdx.z;
  const void* in = z==0 ? w0 : z==1 ? w1 : w2;
  u16*      out  = z==0 ? o0 : z==1 ? o1 : o2;
  const int tid = threadIdx.x;
  const int r0 = blockIdx.y * 64, c0 = blockIdx.x * 64;
  const int rr = tid >> 3;          // 0..31
  const int cc = (tid & 7) * 8;     // 0,8,..,56
#pragma unroll
  for (int rd = 0; rd < 2; rd++){
    int r = rd*32 + rr;
    *(uint4*)&tile[r][cc] = load8(in, (long)(r0 + r)*CDIM + c0 + cc, isbf);
  }
  __syncthreads();
#pragma unroll
  for (int rd = 0; rd < 2; rd++){
    int oc = rd*32 + rr;            // original column offset
    uint4 wv; u32* wp = (u32*)&wv;
#pragma unroll
    for (int t = 0; t < 4; t++){
      u32 lo = tile[cc + 2*t][oc];
      u32 hi = tile[cc + 2*t + 1][oc];
      wp[t] = lo | (hi << 16);
    }
    *(uint4*)(out + (long)(c0 + oc)*CDIM + r0 + cc) = wv;
  }
}

// ---------------- 128x128 GEMM, pipelined K-loop ----------------------------
// A[M,K] @ BT[N,K]^T, K=1024, BK=32, double-buffered LDS, vmcnt(4) pipeline.
// mode 0: out[m*CDIM+n] + bias (dtype per io_isbf)
// mode 1: out[((b*NH+h)*T+t)*DH+d] bf16 (Q/K; scale applied)
// mode 2: out[((b*NH+h)*DH+d)*T+t] bf16 (V transposed; 8B packed stores)
__device__ __forceinline__ void gemm_body(
    const void* __restrict__ A, const u16* __restrict__ BT,
    const void* __restrict__ bias, void* __restrict__ out,
    float scale, int mode, int m0, int n0, int a_isbf, int io_isbf)
{
  __shared__ u16 ldsA[2][128*32];
  __shared__ u16 ldsB[2][128*32];
  const int tid = threadIdx.x;
  const int wid = tid >> 6, lane = tid & 63;
  const int col = lane & 15, quad = lane >> 4;
  const int wm = (wid >> 1) * 64, wn = (wid & 1) * 64;

  // staging map: wave-uniform base + lane*16B  (row = wid*16 + lane/4, chunk = lane%4)
  const int srow = wid*16 + (lane >> 2);
  const int sch  = (lane & 3) * 8;
  const u16* Bg = BT + (long)(n0 + srow) * CDIM + sch;
  const u16* Ag = a_isbf ? ((const u16*)A + (long)(m0 + srow) * CDIM + sch) : nullptr;

  f32x4 acc[4][4] = {};
  const int NK = CDIM / 32;

  auto issueAB = [&](int k0, int pb){
    async16(Bg + k0,           &ldsB[pb][(wid*16)*32]);
    async16(Bg + k0 + 64*CDIM, &ldsB[pb][(wid*16 + 64)*32]);
    if (a_isbf){
      async16(Ag + k0,           &ldsA[pb][(wid*16)*32]);
      async16(Ag + k0 + 64*CDIM, &ldsA[pb][(wid*16 + 64)*32]);
    } else {
      for (int c = tid; c < 512; c += 256){
        const int row = c >> 2, ch = (c & 3) * 8;
        *(uint4*)&ldsA[pb][row*32 + ch] = load8(A, (long)(m0+row)*CDIM + k0 + ch, 0);
      }
    }
  };

  // prologue: two batches in flight
  issueAB(0, 0);
  issueAB(32, 1);
  if (a_isbf) WAITV4L0; else WAITV2L0;
  BARRIER;

  int pb = 0;
  for (int k = 0; k < NK; k++){
    // compute from buf pb
    bf16x8 af[4], bfr[4];
#pragma unroll
    for (int mi = 0; mi < 4; mi++)
      af[mi] = *(const bf16x8*)&ldsA[pb][(wm + mi*16 + col)*32 + quad*8];
#pragma unroll
    for (int ni = 0; ni < 4; ni++)
      bfr[ni] = *(const bf16x8*)&ldsB[pb][(wn + ni*16 + col)*32 + quad*8];
#pragma unroll
    for (int mi = 0; mi < 4; mi++)
#pragma unroll
      for (int ni = 0; ni < 4; ni++)
        acc[mi][ni] = __builtin_amdgcn_mfma_f32_16x16x32_bf16(af[mi], bfr[ni], acc[mi][ni], 0, 0, 0);

    WAITL0; BARRIER;                       // all waves done reading buf pb
    if (k + 2 < NK){
      issueAB((k + 2) * 32, pb);           // overwrite pb (readers done)
      if (a_isbf) WAITV4; else WAITV2;     // batch k+1 drained, k+2 in flight
    } else {
      WAITV0;                              // tail: drain remaining
    }
    BARRIER;                               // batch k+1 visible to all
    pb ^= 1;
  }

  // epilogue
  if (mode == 2){
#pragma unroll
    for (int ni = 0; ni < 4; ni++){
      const int n = n0 + wn + ni*16 + col;
      const int h = n >> 6, d = n & 63;
#pragma unroll
      for (int mi = 0; mi < 4; mi++){
        const int m = m0 + wm + mi*16 + quad*4;
        const int b = m >> 11, t = m & (T_SEQ-1);
        u32 w0 = (u32)f2bf(acc[mi][ni][0]) | ((u32)f2bf(acc[mi][ni][1]) << 16);
        u32 w1 = (u32)f2bf(acc[mi][ni][2]) | ((u32)f2bf(acc[mi][ni][3]) << 16);
        uint2 pk; pk.x = w0; pk.y = w1;
        *(uint2*)((u16*)out + ((long)(b*NH + h)*DHD + d)*T_SEQ + t) = pk;
      }
    }
  } else {
#pragma unroll
    for (int ni = 0; ni < 4; ni++){
      const int n = n0 + wn + ni*16 + col;
      const float bv = bias ? loadf(bias, n, io_isbf) : 0.f;
#pragma unroll
      for (int mi = 0; mi < 4; mi++){
#pragma unroll
        for (int r = 0; r < 4; r++){
          const int m = m0 + wm + mi*16 + quad*4 + r;
          const float v = acc[mi][ni][r] * scale + bv;
          if (mode == 0){
            const long idx = (long)m*CDIM + n;
            if (io_isbf) ((u16*)out)[idx] = f2bf(v);
            else         ((float*)out)[idx] = v;
          } else {
            const int b = m >> 11, t = m & (T_SEQ-1), h = n >> 6, d = n & 63;
            ((u16*)out)[((long)(b*NH + h)*T_SEQ + t)*DHD + d] = f2bf(v);
          }
        }
      }
    }
  }
}

__global__ __launch_bounds__(256) void gemm_qkv(
    const void* __restrict__ x,
    const u16* __restrict__ WqT, const u16* __restrict__ WkT, const u16* __restrict__ WvT,
    u16* __restrict__ Qb, u16* __restrict__ Kb, u16* __restrict__ VTb,
    const int* __restrict__ flag)
{
  const int z = blockIdx.z;
  const u16* BT = z==0 ? WqT : z==1 ? WkT : WvT;
  u16*      dst = z==0 ? Qb  : z==1 ? Kb  : VTb;
  // Q: fold DH^-0.5 and log2(e) so attention exp is a bare v_exp_f32
  const float scale = (z==0) ? 0.125f * 1.44269504f : 1.0f;
  const int mode = (z==2) ? 2 : 1;
  gemm_body(x, BT, nullptr, dst, scale, mode, blockIdx.x*128, blockIdx.y*128, *flag, 1);
}

__global__ __launch_bounds__(256) void gemm_out(
    const u16* __restrict__ Y, const u16* __restrict__ WoT,
    const void* __restrict__ bo, void* __restrict__ out,
    const int* __restrict__ flag)
{
  gemm_body(Y, WoT, bo, out, 1.0f, 0, blockIdx.x*128, blockIdx.y*128, 1, *flag);
}

// ---------------- flash attention, paired tiles + pipelined KV --------------
// Block bx handles Q-tiles bx and 31-bx. Fixed-M softmax (M=16), bias in LDS.
// K/V double-buffered, prefetched j+2 ahead, vmcnt(4) pipeline.
__global__ __launch_bounds__(256) void attn64(
    const u16* __restrict__ Q, const u16* __restrict__ K, const u16* __restrict__ VT,
    const void* __restrict__ rel, u16* __restrict__ Y,
    const int* __restrict__ flag)
{
  __shared__ u16 ldsK[2][64*64];
  __shared__ u16 ldsV[2][64*64];
  __shared__ u16 ldsP[4][16*88];    // per-wave P, row stride 88
  __shared__ float ldsBias[2112];   // biasL[d+63], d = i-j

  const int isbf = *flag;
  const int tid = threadIdx.x, wid = tid >> 6, lane = tid & 63;
  const int col = lane & 15, quad = lane >> 4;
  const int bh = blockIdx.y;
  const int h = bh & (NH - 1);
  const int b = bh >> 4;

  const u16* Qh = Q  + (long)bh * T_SEQ * DHD;
  const u16* Kh = K  + (long)bh * T_SEQ * DHD;
  const u16* Vh = VT + (long)bh * DHD * T_SEQ;
  const long relbase = (long)h * (2*T_SEQ - 1) + (T_SEQ - 1);
  const float MLOG = 16.0f * 1.44269504f;

  auto issueKV = [&](int j0, int pb){
#pragma unroll
    for (int rr = 0; rr < 2; rr++){
      const int rowb = wid*8 + rr*32;
      const int row  = rowb + (lane >> 3);
      const int gc   = (lane & 7) ^ (row & 7);
      async16(Kh + (long)(j0 + row)*DHD + gc*8, &ldsK[pb][rowb*64]);
      async16(Vh + (long)row*T_SEQ + j0 + gc*8, &ldsV[pb][rowb*64]);
    }
  };

  for (int ph = 0; ph < 2; ph++){
    const int ti = ph ? (31 - (int)blockIdx.x) : (int)blockIdx.x;
    const int i0 = ti * 64;

    // stage biasL for d in [-63, i0+63] (plain ds stores; drained at prologue)
    const int nbias = i0 + 127;
    for (int t = tid; t < nbias; t += 256)
      ldsBias[t] = loadf(rel, relbase + t - 63, isbf) * 1.44269504f - MLOG;

    bf16x8 qf0, qf1;   // A-operand: row i0+wid*16+col, k = kb*32+quad*8+j
    {
      const u16* qp = Qh + (long)(i0 + wid*16 + col)*DHD + quad*8;
      qf0 = *(const bf16x8*)qp;
      qf1 = *(const bf16x8*)(qp + 32);
    }

    f32x4 O[4] = {};
    float lsum[4] = {0.f, 0.f, 0.f, 0.f};
    const int irow = i0 + wid*16 + quad*4;

    // prologue: two KV batches in flight
    issueKV(0, 0);
    if (64 <= i0){ issueKV(64, 1); WAITV4L0; } else { WAITV0L0; }
    BARRIER;

    int pb = 0;
    for (int j0 = 0; j0 <= i0; j0 += 64){
      // S = Q K^T from buf pb
      f32x4 s[4] = {};
#pragma unroll
      for (int kb = 0; kb < 2; kb++){
#pragma unroll
        for (int nb = 0; nb < 4; nb++){
          const int row = nb*16 + col;
          const int sl = ((kb*4 + quad) ^ (row & 7)) * 8;
          bf16x8 kf = *(const bf16x8*)&ldsK[pb][row*64 + sl];
          s[nb] = __builtin_amdgcn_mfma_f32_16x16x32_bf16(kb ? qf1 : qf0, kf, s[nb], 0, 0, 0);
        }
      }

      // p = exp2(s + biasL); per-lane row sums
      const bool diag = (j0 == i0);
#pragma unroll
      for (int nb = 0; nb < 4; nb++){
        const int j = j0 + nb*16 + col;
        const float* bp = &ldsBias[irow - j + 63];
#pragma unroll
        for (int r = 0; r < 4; r++){
          float arg = s[nb][r] + bp[r];
          if (diag && (j > irow + r)) arg = -1e9f;
          float p;
          asm volatile("v_exp_f32 %0, %1" : "=v"(p) : "v"(arg));
          s[nb][r] = p;
          lsum[r] += p;
        }
      }

      // P: C-layout -> per-wave LDS -> A-layout (wave-local)
      u16* Pw = ldsP[wid];
#pragma unroll
      for (int nb = 0; nb < 4; nb++)
#pragma unroll
        for (int r = 0; r < 4; r++)
          Pw[(quad*4 + r)*88 + nb*16 + col] = f2bf(s[nb][r]);
      WAITL0;

      // O += P V from buf pb
#pragma unroll
      for (int kb = 0; kb < 2; kb++){
        bf16x8 pf = *(const bf16x8*)&Pw[col*88 + kb*32 + quad*8];
#pragma unroll
        for (int nb = 0; nb < 4; nb++){
          const int row = nb*16 + col;
          const int sl = ((kb*4 + quad) ^ (row & 7)) * 8;
          bf16x8 vf = *(const bf16x8*)&ldsV[pb][row*64 + sl];
          O[nb] = __builtin_amdgcn_mfma_f32_16x16x32_bf16(pf, vf, O[nb], 0, 0, 0);
        }
      }

      WAITL0; BARRIER;                     // all waves done reading buf pb
      if (j0 + 128 <= i0){
        issueKV(j0 + 128, pb);
        WAITV4;                            // batch j0+64 drained, j0+128 in flight
      } else {
        WAITV0;
      }
      BARRIER;
      pb ^= 1;
    }

    // reduce row sums across the 16 cols of each quad
#pragma unroll
    for (int r = 0; r < 4; r++){
      float v = lsum[r];
      v += __shfl_xor(v, 1, 64);
      v += __shfl_xor(v, 2, 64);
      v += __shfl_xor(v, 4, 64);
      v += __shfl_xor(v, 8, 64);
      lsum[r] = v;
    }

    // epilogue: O/l -> Y[(b*T + i)*C + h*64 + d]
#pragma unroll
    for (int nb = 0; nb < 4; nb++){
#pragma unroll
      for (int r = 0; r < 4; r++){
        const int i = irow + r;
        const int d = nb*16 + col;
        Y[((long)(b*T_SEQ + i))*CDIM + h*DHD + d] = f2bf(O[nb][r] / lsum[r]);
      }
    }
  }
}

extern "C" void kernel_launch(void* const* d_in, const int* in_sizes, int n_in,
                              void* d_out, int out_size, void* d_ws, size_t ws_size,
                              hipStream_t stream)
{
  (void)in_sizes; (void)n_in; (void)out_size; (void)ws_size;
  const void* x   = d_in[0];
  const void* Wq  = d_in[1];
  const void* Wk  = d_in[2];
  const void* Wv  = d_in[3];
  const void* Wo  = d_in[4];
  const void* bo  = d_in[5];
  const void* rel = d_in[6];
  // d_in[7] = mask: deterministically causal -> not read

  char* ws = (char*)d_ws;
  const size_t MB = 1024*1024;
  int* flag = (int*)ws;
  char* base = ws + 256;
  u16* WqT = (u16*)(base + 0*MB);
  u16* WkT = (u16*)(base + 2*MB);
  u16* WvT = (u16*)(base + 4*MB);
  u16* Kb  = (u16*)(base + 6*MB);
  u16* VTb = (u16*)(base + 14*MB);    // ..22MB
  u16* Yb  = (u16*)(base + 0*MB);     // phase B: overlaps dead WqT/WkT/WvT
  u16* WoT = (u16*)(base + 8*MB);     // phase B: overlaps dead Kb
  u16* Qb  = (u16*)d_out;             // d_out as scratch for Q (overwritten later)

  dim3 blk(256);
  classify  <<<1, blk, 0, stream>>>((const u32*)x, flag);
  transposeW<<<dim3(16,16,3), blk, 0, stream>>>(Wq, Wk, Wv, WqT, WkT, WvT, flag);
  gemm_qkv  <<<dim3(32,8,3),  blk, 0, stream>>>(x, WqT, WkT, WvT, Qb, Kb, VTb, flag);
  attn64    <<<dim3(16,32),   blk, 0, stream>>>(Qb, Kb, VTb, rel, Yb, flag);
  transposeW<<<dim3(16,16,1), blk, 0, stream>>>(Wo, Wo, Wo, WoT, WoT, WoT, flag);
  gemm_out  <<<dim3(32,8),    blk, 0, stream>>>(Yb, WoT, bo, d_out, flag);
}

// Round 6
// 250.226 us; speedup vs baseline: 1.1787x; 1.1787x over previous
//
#include <hip/hip_runtime.h>
#include <hip/hip_bf16.h>
#include <stdint.h>

// Self-attention, B=2 T=2048 C=1024 H=16 DH=64, causal + relative bias.
// Round 6: revert to round-4 single-buffer 2-barrier structure (round-5 dbuf
// regressed: occupancy loss), add register-prefetch pipelining (CUTLASS
// 2-stage): global loads for k+1 issued into VGPRs before computing k, stored
// to LDS after the barrier. No vmcnt(0) drain before compute. XOR chunk
// swizzle on GEMM LDS tiles to cut fragment-read bank conflicts.
// Invariants: dual-dtype external loads (flag), ws <= 256B + 22MB.
//
// ws layout (offsets from ws+256, bytes):
//   phase A: WqT @0..2M, WkT @2..4M, WvT @4..6M, K @6..14M, V^T @14..22M
//   phase B (weights/K dead): Y @0..8M, WoT @8..10M

#define T_SEQ 2048
#define NH    16
#define DHD   64
#define CDIM  1024

typedef unsigned short u16;
typedef unsigned int   u32;
typedef __attribute__((ext_vector_type(8))) __bf16 bf16x8;   // MFMA A/B operand
typedef __attribute__((ext_vector_type(4))) float f32x4;     // MFMA C/D operand

#define WAITL0   asm volatile("s_waitcnt lgkmcnt(0)" ::: "memory")

__device__ __forceinline__ float bf2f(u16 b){
  union { u32 u; float f; } v; v.u = ((u32)b) << 16; return v.f;
}
__device__ __forceinline__ u16 f2bf(float f){
  union { float f; u32 u; } v; v.f = f;
  u32 r = v.u + 0x7fffu + ((v.u >> 16) & 1u);   // RTNE
  return (u16)(r >> 16);
}

// load 8 consecutive elements as packed bf16 (uint4), from bf16 or f32 source
__device__ __forceinline__ uint4 load8(const void* p, long elem, int isbf){
  if (isbf) return *(const uint4*)((const u16*)p + elem);
  const float* fp = (const float*)p + elem;
  float4 a = *(const float4*)fp, b = *(const float4*)(fp + 4);
  uint4 r;
  r.x = (u32)f2bf(a.x) | ((u32)f2bf(a.y) << 16);
  r.y = (u32)f2bf(a.z) | ((u32)f2bf(a.w) << 16);
  r.z = (u32)f2bf(b.x) | ((u32)f2bf(b.y) << 16);
  r.w = (u32)f2bf(b.z) | ((u32)f2bf(b.w) << 16);
  return r;
}
__device__ __forceinline__ float loadf(const void* p, long idx, int isbf){
  return isbf ? bf2f(((const u16*)p)[idx]) : ((const float*)p)[idx];
}

// ---------------- dtype classifier ------------------------------------------
__global__ __launch_bounds__(256) void classify(const u32* __restrict__ x,
                                                int* __restrict__ flag){
  __shared__ int cnt[256];
  int c = 0;
#pragma unroll
  for (int i = 0; i < 16; i++){
    u32 w = x[threadIdx.x * 16 + i];
    int e = (w >> 7) & 0xFF;
    c += (e >= 110 && e <= 140);
  }
  cnt[threadIdx.x] = c;
  __syncthreads();
  for (int s = 128; s > 0; s >>= 1){
    if ((int)threadIdx.x < s) cnt[threadIdx.x] += cnt[threadIdx.x + s];
    __syncthreads();
  }
  if (threadIdx.x == 0) *flag = (cnt[0] > 2048) ? 1 : 0;   // 1 = bf16
}

// ---------------- weight transpose: out[n][k] = in[k][n], 1024x1024 ----------
__global__ __launch_bounds__(256) void transposeW(
    const void* __restrict__ w0, const void* __restrict__ w1,
    const void* __restrict__ w2,
    u16* __restrict__ o0, u16* __restrict__ o1, u16* __restrict__ o2,
    const int* __restrict__ flag)
{
  __shared__ u16 tile[64][72];
  const int isbf = *flag;
  const int z = blockIdx.z;
  const void* in = z==0 ? w0 : z==1 ? w1 : w2;
  u16*      out  = z==0 ? o0 : z==1 ? o1 : o2;
  const int tid = threadIdx.x;
  const int r0 = blockIdx.y * 64, c0 = blockIdx.x * 64;
  const int rr = tid >> 3;          // 0..31
  const int cc = (tid & 7) * 8;     // 0,8,..,56
#pragma unroll
  for (int rd = 0; rd < 2; rd++){
    int r = rd*32 + rr;
    *(uint4*)&tile[r][cc] = load8(in, (long)(r0 + r)*CDIM + c0 + cc, isbf);
  }
  __syncthreads();
#pragma unroll
  for (int rd = 0; rd < 2; rd++){
    int oc = rd*32 + rr;            // original column offset
    uint4 wv; u32* wp = (u32*)&wv;
#pragma unroll
    for (int t = 0; t < 4; t++){
      u32 lo = tile[cc + 2*t][oc];
      u32 hi = tile[cc + 2*t + 1][oc];
      wp[t] = lo | (hi << 16);
    }
    *(uint4*)(out + (long)(c0 + oc)*CDIM + r0 + cc) = wv;
  }
}

// ---------------- 128x128 GEMM, register-prefetch K-loop --------------------
// A[M,K] @ BT[N,K]^T, K=1024, BK=32, single 16KB-per-operand LDS buffer.
// LDS chunk swizzle: 16B chunk g of row r stored at slot g^(r&3); fragment
// read of k-chunk quad uses slot quad^(r&3).
// mode 0: out[m*CDIM+n] + bias (dtype per io_isbf)
// mode 1: out[((b*NH+h)*T+t)*DH+d] bf16 (Q/K; scale applied)
// mode 2: out[((b*NH+h)*DH+d)*T+t] bf16 (V transposed; 8B packed stores)
__device__ __forceinline__ void gemm_body(
    const void* __restrict__ A, const u16* __restrict__ BT,
    const void* __restrict__ bias, void* __restrict__ out,
    float scale, int mode, int m0, int n0, int a_isbf, int io_isbf)
{
  __shared__ u16 ldsA[128*32];
  __shared__ u16 ldsB[128*32];
  const int tid = threadIdx.x;
  const int wid = tid >> 6, lane = tid & 63;
  const int col = lane & 15, quad = lane >> 4;
  const int wm = (wid >> 1) * 64, wn = (wid & 1) * 64;

  // staging map: thread covers chunks c = tid and tid+256 (row=c>>2, g=c&3)
  const int r0s = tid >> 2, g0 = tid & 3;             // chunk 0
  const int r1s = r0s + 64;                           // chunk 1 (c=tid+256)
  const int sl0 = (g0 ^ (r0s & 3)) * 8;
  const int sl1 = (g0 ^ (r1s & 3)) * 8;

  uint4 rA0, rA1, rB0, rB1;
  auto loadAB = [&](int k0){
    rA0 = load8(A, (long)(m0 + r0s)*CDIM + k0 + g0*8, a_isbf);
    rA1 = load8(A, (long)(m0 + r1s)*CDIM + k0 + g0*8, a_isbf);
    rB0 = *(const uint4*)(BT + (long)(n0 + r0s)*CDIM + k0 + g0*8);
    rB1 = *(const uint4*)(BT + (long)(n0 + r1s)*CDIM + k0 + g0*8);
  };
  auto storeAB = [&](){
    *(uint4*)&ldsA[r0s*32 + sl0] = rA0;
    *(uint4*)&ldsA[r1s*32 + sl1] = rA1;
    *(uint4*)&ldsB[r0s*32 + sl0] = rB0;
    *(uint4*)&ldsB[r1s*32 + sl1] = rB1;
  };

  f32x4 acc[4][4] = {};
  const int NK = CDIM / 32;

  loadAB(0);
  storeAB();
  __syncthreads();

  for (int k = 0; k < NK; k++){
    if (k + 1 < NK) loadAB((k + 1) * 32);   // loads fly during compute

    bf16x8 af[4], bfr[4];
#pragma unroll
    for (int mi = 0; mi < 4; mi++){
      const int r = wm + mi*16 + col;
      af[mi] = *(const bf16x8*)&ldsA[r*32 + ((quad ^ (r & 3)) * 8)];
    }
#pragma unroll
    for (int ni = 0; ni < 4; ni++){
      const int r = wn + ni*16 + col;
      bfr[ni] = *(const bf16x8*)&ldsB[r*32 + ((quad ^ (r & 3)) * 8)];
    }
#pragma unroll
    for (int mi = 0; mi < 4; mi++)
#pragma unroll
      for (int ni = 0; ni < 4; ni++)
        acc[mi][ni] = __builtin_amdgcn_mfma_f32_16x16x32_bf16(af[mi], bfr[ni], acc[mi][ni], 0, 0, 0);

    __syncthreads();                        // all waves done reading LDS
    if (k + 1 < NK){
      storeAB();                            // regs (waited by compiler) -> LDS
      __syncthreads();                      // next tile visible
    }
  }

  // epilogue
  if (mode == 2){
#pragma unroll
    for (int ni = 0; ni < 4; ni++){
      const int n = n0 + wn + ni*16 + col;
      const int h = n >> 6, d = n & 63;
#pragma unroll
      for (int mi = 0; mi < 4; mi++){
        const int m = m0 + wm + mi*16 + quad*4;
        const int b = m >> 11, t = m & (T_SEQ-1);
        uint2 pk;
        pk.x = (u32)f2bf(acc[mi][ni][0]) | ((u32)f2bf(acc[mi][ni][1]) << 16);
        pk.y = (u32)f2bf(acc[mi][ni][2]) | ((u32)f2bf(acc[mi][ni][3]) << 16);
        *(uint2*)((u16*)out + ((long)(b*NH + h)*DHD + d)*T_SEQ + t) = pk;
      }
    }
  } else {
#pragma unroll
    for (int ni = 0; ni < 4; ni++){
      const int n = n0 + wn + ni*16 + col;
      const float bv = bias ? loadf(bias, n, io_isbf) : 0.f;
#pragma unroll
      for (int mi = 0; mi < 4; mi++){
#pragma unroll
        for (int r = 0; r < 4; r++){
          const int m = m0 + wm + mi*16 + quad*4 + r;
          const float v = acc[mi][ni][r] * scale + bv;
          if (mode == 0){
            const long idx = (long)m*CDIM + n;
            if (io_isbf) ((u16*)out)[idx] = f2bf(v);
            else         ((float*)out)[idx] = v;
          } else {
            const int b = m >> 11, t = m & (T_SEQ-1), h = n >> 6, d = n & 63;
            ((u16*)out)[((long)(b*NH + h)*T_SEQ + t)*DHD + d] = f2bf(v);
          }
        }
      }
    }
  }
}

__global__ __launch_bounds__(256) void gemm_qkv(
    const void* __restrict__ x,
    const u16* __restrict__ WqT, const u16* __restrict__ WkT, const u16* __restrict__ WvT,
    u16* __restrict__ Qb, u16* __restrict__ Kb, u16* __restrict__ VTb,
    const int* __restrict__ flag)
{
  const int z = blockIdx.z;
  const u16* BT = z==0 ? WqT : z==1 ? WkT : WvT;
  u16*      dst = z==0 ? Qb  : z==1 ? Kb  : VTb;
  // Q: fold DH^-0.5 and log2(e) so attention exp is a bare v_exp_f32
  const float scale = (z==0) ? 0.125f * 1.44269504f : 1.0f;
  const int mode = (z==2) ? 2 : 1;
  gemm_body(x, BT, nullptr, dst, scale, mode, blockIdx.x*128, blockIdx.y*128, *flag, 1);
}

__global__ __launch_bounds__(256) void gemm_out(
    const u16* __restrict__ Y, const u16* __restrict__ WoT,
    const void* __restrict__ bo, void* __restrict__ out,
    const int* __restrict__ flag)
{
  gemm_body(Y, WoT, bo, out, 1.0f, 0, blockIdx.x*128, blockIdx.y*128, 1, *flag);
}

// ---------------- flash attention, paired tiles + register prefetch ---------
// Block bx handles Q-tiles bx and 31-bx (uniform 33 KV-iters). Fixed-M
// softmax (M=16), bias in LDS. K/V staged single-buffered with register
// prefetch: next tile's global loads issued before computing current tile.
__global__ __launch_bounds__(256) void attn64(
    const u16* __restrict__ Q, const u16* __restrict__ K, const u16* __restrict__ VT,
    const void* __restrict__ rel, u16* __restrict__ Y,
    const int* __restrict__ flag)
{
  __shared__ u16 ldsK[64*64];
  __shared__ u16 ldsV[64*64];
  __shared__ u16 ldsP[4][16*88];    // per-wave P, row stride 88
  __shared__ float ldsBias[2112];   // biasL[d+63], d = i-j

  const int isbf = *flag;
  const int tid = threadIdx.x, wid = tid >> 6, lane = tid & 63;
  const int col = lane & 15, quad = lane >> 4;
  const int bh = blockIdx.y;
  const int h = bh & (NH - 1);
  const int b = bh >> 4;

  const u16* Qh = Q  + (long)bh * T_SEQ * DHD;
  const u16* Kh = K  + (long)bh * T_SEQ * DHD;
  const u16* Vh = VT + (long)bh * DHD * T_SEQ;
  const long relbase = (long)h * (2*T_SEQ - 1) + (T_SEQ - 1);
  const float MLOG = 16.0f * 1.44269504f;

  // staging map: thread covers chunks c = tid, tid+256 (row=c>>3, slot=c&7)
  const int kr0 = tid >> 3, ks = tid & 7;
  const int kr1 = kr0 + 32;
  const int kd0 = (ks ^ (kr0 & 7)) * 8;
  const int kd1 = (ks ^ (kr1 & 7)) * 8;

  uint4 rk0, rk1, rv0, rv1;
  auto loadKV = [&](int j0){
    rk0 = *(const uint4*)(Kh + (long)(j0 + kr0)*DHD + ks*8);
    rk1 = *(const uint4*)(Kh + (long)(j0 + kr1)*DHD + ks*8);
    rv0 = *(const uint4*)(Vh + (long)kr0*T_SEQ + j0 + ks*8);
    rv1 = *(const uint4*)(Vh + (long)kr1*T_SEQ + j0 + ks*8);
  };
  auto storeKV = [&](){
    *(uint4*)&ldsK[kr0*64 + kd0] = rk0;
    *(uint4*)&ldsK[kr1*64 + kd1] = rk1;
    *(uint4*)&ldsV[kr0*64 + kd0] = rv0;
    *(uint4*)&ldsV[kr1*64 + kd1] = rv1;
  };

  for (int ph = 0; ph < 2; ph++){
    const int ti = ph ? (31 - (int)blockIdx.x) : (int)blockIdx.x;
    const int i0 = ti * 64;
    if (ph) __syncthreads();   // phase-A readers done before LDS restage

    // stage biasL for d in [-63, i0+63]
    const int nbias = i0 + 127;
    for (int t = tid; t < nbias; t += 256)
      ldsBias[t] = loadf(rel, relbase + t - 63, isbf) * 1.44269504f - MLOG;

    bf16x8 qf0, qf1;   // A-operand: row i0+wid*16+col, k = kb*32+quad*8+j
    {
      const u16* qp = Qh + (long)(i0 + wid*16 + col)*DHD + quad*8;
      qf0 = *(const bf16x8*)qp;
      qf1 = *(const bf16x8*)(qp + 32);
    }

    f32x4 O[4] = {};
    float lsum[4] = {0.f, 0.f, 0.f, 0.f};
    const int irow = i0 + wid*16 + quad*4;

    loadKV(0);
    storeKV();
    __syncthreads();   // KV tile + bias visible

    for (int j0 = 0; j0 <= i0; j0 += 64){
      const bool have_next = (j0 + 64 <= i0);
      if (have_next) loadKV(j0 + 64);   // loads fly during compute

      // S = Q K^T
      f32x4 s[4] = {};
#pragma unroll
      for (int kb = 0; kb < 2; kb++){
#pragma unroll
        for (int nb = 0; nb < 4; nb++){
          const int row = nb*16 + col;
          const int sl = ((kb*4 + quad) ^ (row & 7)) * 8;
          bf16x8 kf = *(const bf16x8*)&ldsK[row*64 + sl];
          s[nb] = __builtin_amdgcn_mfma_f32_16x16x32_bf16(kb ? qf1 : qf0, kf, s[nb], 0, 0, 0);
        }
      }

      // p = exp2(s + biasL); per-lane row sums
      const bool diag = (j0 == i0);
#pragma unroll
      for (int nb = 0; nb < 4; nb++){
        const int j = j0 + nb*16 + col;
        const float* bp = &ldsBias[irow - j + 63];
#pragma unroll
        for (int r = 0; r < 4; r++){
          float arg = s[nb][r] + bp[r];
          if (diag && (j > irow + r)) arg = -1e9f;
          float p;
          asm volatile("v_exp_f32 %0, %1" : "=v"(p) : "v"(arg));
          s[nb][r] = p;
          lsum[r] += p;
        }
      }

      // P: C-layout -> per-wave LDS -> A-layout (wave-local ordering)
      u16* Pw = ldsP[wid];
#pragma unroll
      for (int nb = 0; nb < 4; nb++)
#pragma unroll
        for (int r = 0; r < 4; r++)
          Pw[(quad*4 + r)*88 + nb*16 + col] = f2bf(s[nb][r]);
      WAITL0;

      // O += P V
#pragma unroll
      for (int kb = 0; kb < 2; kb++){
        bf16x8 pf = *(const bf16x8*)&Pw[col*88 + kb*32 + quad*8];
#pragma unroll
        for (int nb = 0; nb < 4; nb++){
          const int row = nb*16 + col;
          const int sl = ((kb*4 + quad) ^ (row & 7)) * 8;
          bf16x8 vf = *(const bf16x8*)&ldsV[row*64 + sl];
          O[nb] = __builtin_amdgcn_mfma_f32_16x16x32_bf16(pf, vf, O[nb], 0, 0, 0);
        }
      }

      __syncthreads();                 // all waves done reading K/V
      if (have_next){
        storeKV();                     // prefetched tile -> LDS
        __syncthreads();
      }
    }

    // reduce row sums across the 16 cols of each quad
#pragma unroll
    for (int r = 0; r < 4; r++){
      float v = lsum[r];
      v += __shfl_xor(v, 1, 64);
      v += __shfl_xor(v, 2, 64);
      v += __shfl_xor(v, 4, 64);
      v += __shfl_xor(v, 8, 64);
      lsum[r] = v;
    }

    // epilogue: O/l -> Y[(b*T + i)*C + h*64 + d]
#pragma unroll
    for (int nb = 0; nb < 4; nb++){
#pragma unroll
      for (int r = 0; r < 4; r++){
        const int i = irow + r;
        const int d = nb*16 + col;
        Y[((long)(b*T_SEQ + i))*CDIM + h*DHD + d] = f2bf(O[nb][r] / lsum[r]);
      }
    }
  }
}

extern "C" void kernel_launch(void* const* d_in, const int* in_sizes, int n_in,
                              void* d_out, int out_size, void* d_ws, size_t ws_size,
                              hipStream_t stream)
{
  (void)in_sizes; (void)n_in; (void)out_size; (void)ws_size;
  const void* x   = d_in[0];
  const void* Wq  = d_in[1];
  const void* Wk  = d_in[2];
  const void* Wv  = d_in[3];
  const void* Wo  = d_in[4];
  const void* bo  = d_in[5];
  const void* rel = d_in[6];
  // d_in[7] = mask: deterministically causal -> not read

  char* ws = (char*)d_ws;
  const size_t MB = 1024*1024;
  int* flag = (int*)ws;
  char* base = ws + 256;
  u16* WqT = (u16*)(base + 0*MB);
  u16* WkT = (u16*)(base + 2*MB);
  u16* WvT = (u16*)(base + 4*MB);
  u16* Kb  = (u16*)(base + 6*MB);
  u16* VTb = (u16*)(base + 14*MB);    // ..22MB
  u16* Yb  = (u16*)(base + 0*MB);     // phase B: overlaps dead WqT/WkT/WvT
  u16* WoT = (u16*)(base + 8*MB);     // phase B: overlaps dead Kb
  u16* Qb  = (u16*)d_out;             // d_out as scratch for Q (overwritten later)

  dim3 blk(256);
  classify  <<<1, blk, 0, stream>>>((const u32*)x, flag);
  transposeW<<<dim3(16,16,3), blk, 0, stream>>>(Wq, Wk, Wv, WqT, WkT, WvT, flag);
  gemm_qkv  <<<dim3(32,8,3),  blk, 0, stream>>>(x, WqT, WkT, WvT, Qb, Kb, VTb, flag);
  attn64    <<<dim3(16,32),   blk, 0, stream>>>(Qb, Kb, VTb, rel, Yb, flag);
  transposeW<<<dim3(16,16,1), blk, 0, stream>>>(Wo, Wo, Wo, WoT, WoT, WoT, flag);
  gemm_out  <<<dim3(32,8),    blk, 0, stream>>>(Yb, WoT, bo, d_out, flag);
}

// Round 7
// 245.354 us; speedup vs baseline: 1.2021x; 1.0199x over previous
//
#include <hip/hip_runtime.h>
#include <hip/hip_bf16.h>
#include <stdint.h>

// Self-attention, B=2 T=2048 C=1024 H=16 DH=64, causal + relative bias.
// Round 7: (a) XCD-aware block swizzle in attn64 — each XCD owns 4 heads so
// K/V (2MB) fits its 4MB L2 (round-6 FETCH showed 119MB HBM re-reads of a
// 16MB footprint); (b) native __bf16 casts replace 5-op manual RTNE f2bf.
// Structure otherwise identical to round 6 (register-prefetch, single-buffer).
// Invariants: dual-dtype external loads (flag), ws <= 256B + 22MB.
//
// ws layout (offsets from ws+256, bytes):
//   phase A: WqT @0..2M, WkT @2..4M, WvT @4..6M, K @6..14M, V^T @14..22M
//   phase B (weights/K dead): Y @0..8M, WoT @8..10M

#define T_SEQ 2048
#define NH    16
#define DHD   64
#define CDIM  1024

typedef unsigned short u16;
typedef unsigned int   u32;
typedef __attribute__((ext_vector_type(8))) __bf16 bf16x8;   // MFMA A/B operand
typedef __attribute__((ext_vector_type(4))) float f32x4;     // MFMA C/D operand

#define WAITL0   asm volatile("s_waitcnt lgkmcnt(0)" ::: "memory")

__device__ __forceinline__ float bf2f(u16 b){
  union { u32 u; float f; } v; v.u = ((u32)b) << 16; return v.f;
}
__device__ __forceinline__ u16 f2bf(float f){
  union { __bf16 h; u16 u; } v; v.h = (__bf16)f;   // native cvt on gfx950
  return v.u;
}

// load 8 consecutive elements as packed bf16 (uint4), from bf16 or f32 source
__device__ __forceinline__ uint4 load8(const void* p, long elem, int isbf){
  if (isbf) return *(const uint4*)((const u16*)p + elem);
  const float* fp = (const float*)p + elem;
  float4 a = *(const float4*)fp, b = *(const float4*)(fp + 4);
  uint4 r;
  r.x = (u32)f2bf(a.x) | ((u32)f2bf(a.y) << 16);
  r.y = (u32)f2bf(a.z) | ((u32)f2bf(a.w) << 16);
  r.z = (u32)f2bf(b.x) | ((u32)f2bf(b.y) << 16);
  r.w = (u32)f2bf(b.z) | ((u32)f2bf(b.w) << 16);
  return r;
}
__device__ __forceinline__ float loadf(const void* p, long idx, int isbf){
  return isbf ? bf2f(((const u16*)p)[idx]) : ((const float*)p)[idx];
}

// ---------------- dtype classifier ------------------------------------------
__global__ __launch_bounds__(256) void classify(const u32* __restrict__ x,
                                                int* __restrict__ flag){
  __shared__ int cnt[256];
  int c = 0;
#pragma unroll
  for (int i = 0; i < 16; i++){
    u32 w = x[threadIdx.x * 16 + i];
    int e = (w >> 7) & 0xFF;
    c += (e >= 110 && e <= 140);
  }
  cnt[threadIdx.x] = c;
  __syncthreads();
  for (int s = 128; s > 0; s >>= 1){
    if ((int)threadIdx.x < s) cnt[threadIdx.x] += cnt[threadIdx.x + s];
    __syncthreads();
  }
  if (threadIdx.x == 0) *flag = (cnt[0] > 2048) ? 1 : 0;   // 1 = bf16
}

// ---------------- weight transpose: out[n][k] = in[k][n], 1024x1024 ----------
__global__ __launch_bounds__(256) void transposeW(
    const void* __restrict__ w0, const void* __restrict__ w1,
    const void* __restrict__ w2,
    u16* __restrict__ o0, u16* __restrict__ o1, u16* __restrict__ o2,
    const int* __restrict__ flag)
{
  __shared__ u16 tile[64][72];
  const int isbf = *flag;
  const int z = blockIdx.z;
  const void* in = z==0 ? w0 : z==1 ? w1 : w2;
  u16*      out  = z==0 ? o0 : z==1 ? o1 : o2;
  const int tid = threadIdx.x;
  const int r0 = blockIdx.y * 64, c0 = blockIdx.x * 64;
  const int rr = tid >> 3;          // 0..31
  const int cc = (tid & 7) * 8;     // 0,8,..,56
#pragma unroll
  for (int rd = 0; rd < 2; rd++){
    int r = rd*32 + rr;
    *(uint4*)&tile[r][cc] = load8(in, (long)(r0 + r)*CDIM + c0 + cc, isbf);
  }
  __syncthreads();
#pragma unroll
  for (int rd = 0; rd < 2; rd++){
    int oc = rd*32 + rr;            // original column offset
    uint4 wv; u32* wp = (u32*)&wv;
#pragma unroll
    for (int t = 0; t < 4; t++){
      u32 lo = tile[cc + 2*t][oc];
      u32 hi = tile[cc + 2*t + 1][oc];
      wp[t] = lo | (hi << 16);
    }
    *(uint4*)(out + (long)(c0 + oc)*CDIM + r0 + cc) = wv;
  }
}

// ---------------- 128x128 GEMM, register-prefetch K-loop --------------------
// A[M,K] @ BT[N,K]^T, K=1024, BK=32, single 16KB-per-operand LDS buffer.
// LDS chunk swizzle: 16B chunk g of row r stored at slot g^(r&3).
// mode 0: out[m*CDIM+n] + bias (dtype per io_isbf)
// mode 1: out[((b*NH+h)*T+t)*DH+d] bf16 (Q/K; scale applied)
// mode 2: out[((b*NH+h)*DH+d)*T+t] bf16 (V transposed; 8B packed stores)
__device__ __forceinline__ void gemm_body(
    const void* __restrict__ A, const u16* __restrict__ BT,
    const void* __restrict__ bias, void* __restrict__ out,
    float scale, int mode, int m0, int n0, int a_isbf, int io_isbf)
{
  __shared__ u16 ldsA[128*32];
  __shared__ u16 ldsB[128*32];
  const int tid = threadIdx.x;
  const int wid = tid >> 6, lane = tid & 63;
  const int col = lane & 15, quad = lane >> 4;
  const int wm = (wid >> 1) * 64, wn = (wid & 1) * 64;

  // staging map: thread covers chunks c = tid and tid+256 (row=c>>2, g=c&3)
  const int r0s = tid >> 2, g0 = tid & 3;             // chunk 0
  const int r1s = r0s + 64;                           // chunk 1 (c=tid+256)
  const int sl0 = (g0 ^ (r0s & 3)) * 8;
  const int sl1 = (g0 ^ (r1s & 3)) * 8;

  uint4 rA0, rA1, rB0, rB1;
  auto loadAB = [&](int k0){
    rA0 = load8(A, (long)(m0 + r0s)*CDIM + k0 + g0*8, a_isbf);
    rA1 = load8(A, (long)(m0 + r1s)*CDIM + k0 + g0*8, a_isbf);
    rB0 = *(const uint4*)(BT + (long)(n0 + r0s)*CDIM + k0 + g0*8);
    rB1 = *(const uint4*)(BT + (long)(n0 + r1s)*CDIM + k0 + g0*8);
  };
  auto storeAB = [&](){
    *(uint4*)&ldsA[r0s*32 + sl0] = rA0;
    *(uint4*)&ldsA[r1s*32 + sl1] = rA1;
    *(uint4*)&ldsB[r0s*32 + sl0] = rB0;
    *(uint4*)&ldsB[r1s*32 + sl1] = rB1;
  };

  f32x4 acc[4][4] = {};
  const int NK = CDIM / 32;

  loadAB(0);
  storeAB();
  __syncthreads();

  for (int k = 0; k < NK; k++){
    if (k + 1 < NK) loadAB((k + 1) * 32);   // loads fly during compute

    bf16x8 af[4], bfr[4];
#pragma unroll
    for (int mi = 0; mi < 4; mi++){
      const int r = wm + mi*16 + col;
      af[mi] = *(const bf16x8*)&ldsA[r*32 + ((quad ^ (r & 3)) * 8)];
    }
#pragma unroll
    for (int ni = 0; ni < 4; ni++){
      const int r = wn + ni*16 + col;
      bfr[ni] = *(const bf16x8*)&ldsB[r*32 + ((quad ^ (r & 3)) * 8)];
    }
#pragma unroll
    for (int mi = 0; mi < 4; mi++)
#pragma unroll
      for (int ni = 0; ni < 4; ni++)
        acc[mi][ni] = __builtin_amdgcn_mfma_f32_16x16x32_bf16(af[mi], bfr[ni], acc[mi][ni], 0, 0, 0);

    __syncthreads();                        // all waves done reading LDS
    if (k + 1 < NK){
      storeAB();                            // regs (waited by compiler) -> LDS
      __syncthreads();                      // next tile visible
    }
  }

  // epilogue
  if (mode == 2){
#pragma unroll
    for (int ni = 0; ni < 4; ni++){
      const int n = n0 + wn + ni*16 + col;
      const int h = n >> 6, d = n & 63;
#pragma unroll
      for (int mi = 0; mi < 4; mi++){
        const int m = m0 + wm + mi*16 + quad*4;
        const int b = m >> 11, t = m & (T_SEQ-1);
        uint2 pk;
        pk.x = (u32)f2bf(acc[mi][ni][0]) | ((u32)f2bf(acc[mi][ni][1]) << 16);
        pk.y = (u32)f2bf(acc[mi][ni][2]) | ((u32)f2bf(acc[mi][ni][3]) << 16);
        *(uint2*)((u16*)out + ((long)(b*NH + h)*DHD + d)*T_SEQ + t) = pk;
      }
    }
  } else {
#pragma unroll
    for (int ni = 0; ni < 4; ni++){
      const int n = n0 + wn + ni*16 + col;
      const float bv = bias ? loadf(bias, n, io_isbf) : 0.f;
#pragma unroll
      for (int mi = 0; mi < 4; mi++){
#pragma unroll
        for (int r = 0; r < 4; r++){
          const int m = m0 + wm + mi*16 + quad*4 + r;
          const float v = acc[mi][ni][r] * scale + bv;
          if (mode == 0){
            const long idx = (long)m*CDIM + n;
            if (io_isbf) ((u16*)out)[idx] = f2bf(v);
            else         ((float*)out)[idx] = v;
          } else {
            const int b = m >> 11, t = m & (T_SEQ-1), h = n >> 6, d = n & 63;
            ((u16*)out)[((long)(b*NH + h)*T_SEQ + t)*DHD + d] = f2bf(v);
          }
        }
      }
    }
  }
}

__global__ __launch_bounds__(256) void gemm_qkv(
    const void* __restrict__ x,
    const u16* __restrict__ WqT, const u16* __restrict__ WkT, const u16* __restrict__ WvT,
    u16* __restrict__ Qb, u16* __restrict__ Kb, u16* __restrict__ VTb,
    const int* __restrict__ flag)
{
  const int z = blockIdx.z;
  const u16* BT = z==0 ? WqT : z==1 ? WkT : WvT;
  u16*      dst = z==0 ? Qb  : z==1 ? Kb  : VTb;
  // Q: fold DH^-0.5 and log2(e) so attention exp is a bare v_exp_f32
  const float scale = (z==0) ? 0.125f * 1.44269504f : 1.0f;
  const int mode = (z==2) ? 2 : 1;
  gemm_body(x, BT, nullptr, dst, scale, mode, blockIdx.x*128, blockIdx.y*128, *flag, 1);
}

__global__ __launch_bounds__(256) void gemm_out(
    const u16* __restrict__ Y, const u16* __restrict__ WoT,
    const void* __restrict__ bo, void* __restrict__ out,
    const int* __restrict__ flag)
{
  gemm_body(Y, WoT, bo, out, 1.0f, 0, blockIdx.x*128, blockIdx.y*128, 1, *flag);
}

// ---------------- flash attention, paired tiles + register prefetch ---------
// XCD-aware swizzle: linear id l -> xcd = l&7 owns heads [xcd*4, xcd*4+4),
// so each XCD's K/V working set is 2MB (fits 4MB L2). Block handles Q-tiles
// bx and 31-bx (uniform 33 KV-iters). Fixed-M softmax (M=16), bias in LDS.
__global__ __launch_bounds__(256) void attn64(
    const u16* __restrict__ Q, const u16* __restrict__ K, const u16* __restrict__ VT,
    const void* __restrict__ rel, u16* __restrict__ Y,
    const int* __restrict__ flag)
{
  __shared__ u16 ldsK[64*64];
  __shared__ u16 ldsV[64*64];
  __shared__ u16 ldsP[4][16*88];    // per-wave P, row stride 88
  __shared__ float ldsBias[2112];   // biasL[d+63], d = i-j

  const int isbf = *flag;
  const int tid = threadIdx.x, wid = tid >> 6, lane = tid & 63;
  const int col = lane & 15, quad = lane >> 4;

  // XCD-aware decode of (bh, bx) from linear workgroup id (dispatch
  // round-robins linear id across the 8 XCDs)
  const int l = (int)blockIdx.x + 16 * (int)blockIdx.y;
  const int xcd = l & 7, s = l >> 3;
  const int bh = xcd * 4 + (s & 3);
  const int bx = s >> 2;            // virtual Q-tile index in [0,16)

  const int h = bh & (NH - 1);
  const int b = bh >> 4;

  const u16* Qh = Q  + (long)bh * T_SEQ * DHD;
  const u16* Kh = K  + (long)bh * T_SEQ * DHD;
  const u16* Vh = VT + (long)bh * DHD * T_SEQ;
  const long relbase = (long)h * (2*T_SEQ - 1) + (T_SEQ - 1);
  const float MLOG = 16.0f * 1.44269504f;

  // staging map: thread covers chunks c = tid, tid+256 (row=c>>3, slot=c&7)
  const int kr0 = tid >> 3, ks = tid & 7;
  const int kr1 = kr0 + 32;
  const int kd0 = (ks ^ (kr0 & 7)) * 8;
  const int kd1 = (ks ^ (kr1 & 7)) * 8;

  uint4 rk0, rk1, rv0, rv1;
  auto loadKV = [&](int j0){
    rk0 = *(const uint4*)(Kh + (long)(j0 + kr0)*DHD + ks*8);
    rk1 = *(const uint4*)(Kh + (long)(j0 + kr1)*DHD + ks*8);
    rv0 = *(const uint4*)(Vh + (long)kr0*T_SEQ + j0 + ks*8);
    rv1 = *(const uint4*)(Vh + (long)kr1*T_SEQ + j0 + ks*8);
  };
  auto storeKV = [&](){
    *(uint4*)&ldsK[kr0*64 + kd0] = rk0;
    *(uint4*)&ldsK[kr1*64 + kd1] = rk1;
    *(uint4*)&ldsV[kr0*64 + kd0] = rv0;
    *(uint4*)&ldsV[kr1*64 + kd1] = rv1;
  };

  for (int ph = 0; ph < 2; ph++){
    const int ti = ph ? (31 - bx) : bx;
    const int i0 = ti * 64;
    if (ph) __syncthreads();   // phase-A readers done before LDS restage

    // stage biasL for d in [-63, i0+63]
    const int nbias = i0 + 127;
    for (int t = tid; t < nbias; t += 256)
      ldsBias[t] = loadf(rel, relbase + t - 63, isbf) * 1.44269504f - MLOG;

    bf16x8 qf0, qf1;   // A-operand: row i0+wid*16+col, k = kb*32+quad*8+j
    {
      const u16* qp = Qh + (long)(i0 + wid*16 + col)*DHD + quad*8;
      qf0 = *(const bf16x8*)qp;
      qf1 = *(const bf16x8*)(qp + 32);
    }

    f32x4 O[4] = {};
    float lsum[4] = {0.f, 0.f, 0.f, 0.f};
    const int irow = i0 + wid*16 + quad*4;

    loadKV(0);
    storeKV();
    __syncthreads();   // KV tile + bias visible

    for (int j0 = 0; j0 <= i0; j0 += 64){
      const bool have_next = (j0 + 64 <= i0);
      if (have_next) loadKV(j0 + 64);   // loads fly during compute

      // S = Q K^T
      f32x4 s[4] = {};
#pragma unroll
      for (int kb = 0; kb < 2; kb++){
#pragma unroll
        for (int nb = 0; nb < 4; nb++){
          const int row = nb*16 + col;
          const int sl = ((kb*4 + quad) ^ (row & 7)) * 8;
          bf16x8 kf = *(const bf16x8*)&ldsK[row*64 + sl];
          s[nb] = __builtin_amdgcn_mfma_f32_16x16x32_bf16(kb ? qf1 : qf0, kf, s[nb], 0, 0, 0);
        }
      }

      // p = exp2(s + biasL); per-lane row sums
      const bool diag = (j0 == i0);
#pragma unroll
      for (int nb = 0; nb < 4; nb++){
        const int j = j0 + nb*16 + col;
        const float* bp = &ldsBias[irow - j + 63];
#pragma unroll
        for (int r = 0; r < 4; r++){
          float arg = s[nb][r] + bp[r];
          if (diag && (j > irow + r)) arg = -1e9f;
          float p;
          asm volatile("v_exp_f32 %0, %1" : "=v"(p) : "v"(arg));
          s[nb][r] = p;
          lsum[r] += p;
        }
      }

      // P: C-layout -> per-wave LDS -> A-layout (wave-local ordering)
      u16* Pw = ldsP[wid];
#pragma unroll
      for (int nb = 0; nb < 4; nb++)
#pragma unroll
        for (int r = 0; r < 4; r++)
          Pw[(quad*4 + r)*88 + nb*16 + col] = f2bf(s[nb][r]);
      WAITL0;

      // O += P V
#pragma unroll
      for (int kb = 0; kb < 2; kb++){
        bf16x8 pf = *(const bf16x8*)&Pw[col*88 + kb*32 + quad*8];
#pragma unroll
        for (int nb = 0; nb < 4; nb++){
          const int row = nb*16 + col;
          const int sl = ((kb*4 + quad) ^ (row & 7)) * 8;
          bf16x8 vf = *(const bf16x8*)&ldsV[row*64 + sl];
          O[nb] = __builtin_amdgcn_mfma_f32_16x16x32_bf16(pf, vf, O[nb], 0, 0, 0);
        }
      }

      __syncthreads();                 // all waves done reading K/V
      if (have_next){
        storeKV();                     // prefetched tile -> LDS
        __syncthreads();
      }
    }

    // reduce row sums across the 16 cols of each quad
#pragma unroll
    for (int r = 0; r < 4; r++){
      float v = lsum[r];
      v += __shfl_xor(v, 1, 64);
      v += __shfl_xor(v, 2, 64);
      v += __shfl_xor(v, 4, 64);
      v += __shfl_xor(v, 8, 64);
      lsum[r] = v;
    }

    // epilogue: O/l -> Y[(b*T + i)*C + h*64 + d]
#pragma unroll
    for (int nb = 0; nb < 4; nb++){
#pragma unroll
      for (int r = 0; r < 4; r++){
        const int i = irow + r;
        const int d = nb*16 + col;
        Y[((long)(b*T_SEQ + i))*CDIM + h*DHD + d] = f2bf(O[nb][r] / lsum[r]);
      }
    }
  }
}

extern "C" void kernel_launch(void* const* d_in, const int* in_sizes, int n_in,
                              void* d_out, int out_size, void* d_ws, size_t ws_size,
                              hipStream_t stream)
{
  (void)in_sizes; (void)n_in; (void)out_size; (void)ws_size;
  const void* x   = d_in[0];
  const void* Wq  = d_in[1];
  const void* Wk  = d_in[2];
  const void* Wv  = d_in[3];
  const void* Wo  = d_in[4];
  const void* bo  = d_in[5];
  const void* rel = d_in[6];
  // d_in[7] = mask: deterministically causal -> not read

  char* ws = (char*)d_ws;
  const size_t MB = 1024*1024;
  int* flag = (int*)ws;
  char* base = ws + 256;
  u16* WqT = (u16*)(base + 0*MB);
  u16* WkT = (u16*)(base + 2*MB);
  u16* WvT = (u16*)(base + 4*MB);
  u16* Kb  = (u16*)(base + 6*MB);
  u16* VTb = (u16*)(base + 14*MB);    // ..22MB
  u16* Yb  = (u16*)(base + 0*MB);     // phase B: overlaps dead WqT/WkT/WvT
  u16* WoT = (u16*)(base + 8*MB);     // phase B: overlaps dead Kb
  u16* Qb  = (u16*)d_out;             // d_out as scratch for Q (overwritten later)

  dim3 blk(256);
  classify  <<<1, blk, 0, stream>>>((const u32*)x, flag);
  transposeW<<<dim3(16,16,3), blk, 0, stream>>>(Wq, Wk, Wv, WqT, WkT, WvT, flag);
  gemm_qkv  <<<dim3(32,8,3),  blk, 0, stream>>>(x, WqT, WkT, WvT, Qb, Kb, VTb, flag);
  attn64    <<<dim3(16,32),   blk, 0, stream>>>(Qb, Kb, VTb, rel, Yb, flag);
  transposeW<<<dim3(16,16,1), blk, 0, stream>>>(Wo, Wo, Wo, WoT, WoT, WoT, flag);
  gemm_out  <<<dim3(32,8),    blk, 0, stream>>>(Yb, WoT, bo, d_out, flag);
}